// Round 1
// baseline (7197.672 us; speedup 1.0000x reference)
//
#include <hip/hip_runtime.h>
#include <stdint.h>

#define B_DIM 256
#define P_DIM 4096
#define L_DIM 8192
#define NSTEPS 50
#define STEP 0.1f
#define LAM 0.1f

typedef __attribute__((ext_vector_type(8))) short bf16x8;
typedef __attribute__((ext_vector_type(4))) float f32x4;

__device__ __forceinline__ unsigned short f2bf(float f) {
    union { float f; uint32_t u; } x; x.f = f;
    uint32_t r = (x.u + 0x7FFF + ((x.u >> 16) & 1)) >> 16;
    return (unsigned short)r;
}

// ---------------- cast x (f32 -> bf16), vectorized ----------------
__global__ void cast_x_kernel(const float* __restrict__ in, unsigned short* __restrict__ out, int n) {
    int i = (blockIdx.x * blockDim.x + threadIdx.x) * 4;
    if (i < n) {
        float4 v = *(const float4*)&in[i];
        ushort4 o;
        o.x = f2bf(v.x); o.y = f2bf(v.y); o.z = f2bf(v.z); o.w = f2bf(v.w);
        *(ushort4*)&out[i] = o;
    }
}

// ------------- cast + transpose w: w[P][L] f32 -> w_bf[P][L], wT_bf[L][P] -------------
__global__ void cast_transpose_w(const float* __restrict__ w,
                                 unsigned short* __restrict__ w_bf,
                                 unsigned short* __restrict__ wT_bf) {
    __shared__ float tile[32][33];
    int c0 = blockIdx.x * 32;  // latent (col of w)
    int r0 = blockIdx.y * 32;  // pixel (row of w)
    int tx = threadIdx.x, ty = threadIdx.y;  // 32 x 8
#pragma unroll
    for (int i = ty; i < 32; i += 8) {
        float v = w[(size_t)(r0 + i) * L_DIM + c0 + tx];
        tile[i][tx] = v;
        w_bf[(size_t)(r0 + i) * L_DIM + c0 + tx] = f2bf(v);
    }
    __syncthreads();
#pragma unroll
    for (int i = ty; i < 32; i += 8) {
        wT_bf[(size_t)(c0 + i) * P_DIM + r0 + tx] = f2bf(tile[tx][i]);
    }
}

// ---------------- NT GEMM: C[M,N] = A[M,K] @ Bt[N,K]^T, bf16 in, f32 accum ----------------
// EPI: 0 = gram (C_bf16 = acc - I)
//      1 = b    (b=acc; u=0.1*acc; a=thr(u))
//      2 = iter (u = 0.9u + 0.1b - 0.1*acc; a=thr(u))
//      3 = recon (Cf = acc)
template <int BM, int BN, int BK, int WM, int WN, int EPI>
__global__ __launch_bounds__((BM / WM) * (BN / WN) * 64)
void gemm_nt(const unsigned short* __restrict__ A,
             const unsigned short* __restrict__ Bt,
             int N, int K,
             float* __restrict__ Cf, unsigned short* __restrict__ Cbf,
             const float* __restrict__ bvec, float* __restrict__ uvec,
             unsigned short* __restrict__ aout) {
    constexpr int NWAVES = (BM / WM) * (BN / WN);
    constexpr int WN_CNT = BN / WN;
    constexpr int MF = WM / 16, NF = WN / 16;

    __shared__ __align__(16) unsigned short As[BM * BK];
    __shared__ __align__(16) unsigned short Bs[BN * BK];

    const int tid = threadIdx.x;
    const int w = tid >> 6;
    const int l = tid & 63;
    const int wr = w / WN_CNT, wc = w % WN_CNT;
    const int row0 = blockIdx.y * BM;
    const int col0 = blockIdx.x * BN;

    f32x4 acc[MF][NF] = {};

    const int lrow = l >> 3;        // row within 8-row chunk
    const int lcol = (l & 7) * 8;   // k offset (elements)

    for (int k0 = 0; k0 < K; k0 += BK) {
        // stage A tile (BM x BK) via async global->LDS, 16B/lane
#pragma unroll
        for (int i = 0; i < BM / (8 * NWAVES); ++i) {
            int chunk = i * NWAVES + w;
            const unsigned short* g = A + (size_t)(row0 + chunk * 8 + lrow) * K + (k0 + lcol);
            __builtin_amdgcn_global_load_lds(
                (const __attribute__((address_space(1))) void*)g,
                (__attribute__((address_space(3))) void*)(As + chunk * 512), 16, 0, 0);
        }
        // stage Bt tile (BN x BK)
#pragma unroll
        for (int i = 0; i < BN / (8 * NWAVES); ++i) {
            int chunk = i * NWAVES + w;
            const unsigned short* g = Bt + (size_t)(col0 + chunk * 8 + lrow) * K + (k0 + lcol);
            __builtin_amdgcn_global_load_lds(
                (const __attribute__((address_space(1))) void*)g,
                (__attribute__((address_space(3))) void*)(Bs + chunk * 512), 16, 0, 0);
        }
        asm volatile("s_waitcnt vmcnt(0)" ::: "memory");
        __syncthreads();

#pragma unroll
        for (int kk = 0; kk < BK; kk += 32) {
            const int kb = kk + (l >> 4) * 8;
            bf16x8 af[MF], bfr[NF];
#pragma unroll
            for (int mf = 0; mf < MF; ++mf)
                af[mf] = *(const bf16x8*)&As[(wr * WM + mf * 16 + (l & 15)) * BK + kb];
#pragma unroll
            for (int nf = 0; nf < NF; ++nf)
                bfr[nf] = *(const bf16x8*)&Bs[(wc * WN + nf * 16 + (l & 15)) * BK + kb];
#pragma unroll
            for (int mf = 0; mf < MF; ++mf)
#pragma unroll
                for (int nf = 0; nf < NF; ++nf)
                    acc[mf][nf] = __builtin_amdgcn_mfma_f32_16x16x32_bf16(
                        af[mf], bfr[nf], acc[mf][nf], 0, 0, 0);
        }
        __syncthreads();
    }

    // epilogue: C/D layout col = l&15, row = (l>>4)*4 + j  [m89-verified]
    const int er = (l >> 4) * 4;
    const int ec = l & 15;
#pragma unroll
    for (int mf = 0; mf < MF; ++mf) {
#pragma unroll
        for (int nf = 0; nf < NF; ++nf) {
#pragma unroll
            for (int j = 0; j < 4; ++j) {
                int gr = row0 + wr * WM + mf * 16 + er + j;
                int gc = col0 + wc * WN + nf * 16 + ec;
                size_t idx = (size_t)gr * N + gc;
                float v = acc[mf][nf][j];
                if constexpr (EPI == 0) {
                    if (gr == gc) v -= 1.0f;
                    Cbf[idx] = f2bf(v);
                } else if constexpr (EPI == 1) {
                    Cf[idx] = v;
                    float u0 = STEP * v;
                    uvec[idx] = u0;
                    float a = (u0 > LAM) ? (u0 - LAM) : 0.0f;
                    aout[idx] = f2bf(a);
                } else if constexpr (EPI == 2) {
                    float un = (1.0f - STEP) * uvec[idx] + STEP * bvec[idx] - STEP * v;
                    uvec[idx] = un;
                    float a = (un > LAM) ? (un - LAM) : 0.0f;
                    aout[idx] = f2bf(a);
                } else {
                    Cf[idx] = v;
                }
            }
        }
    }
}

extern "C" void kernel_launch(void* const* d_in, const int* in_sizes, int n_in,
                              void* d_out, int out_size, void* d_ws, size_t ws_size,
                              hipStream_t stream) {
    (void)in_sizes; (void)n_in; (void)out_size; (void)ws_size;
    const float* x = (const float*)d_in[0];
    const float* w = (const float*)d_in[1];
    float* out = (float*)d_out;

    char* ws = (char*)d_ws;
    unsigned short* wT  = (unsigned short*)ws;                    // [L][P] 64MB
    unsigned short* wbf = wT + (size_t)L_DIM * P_DIM;             // [P][L] 64MB
    unsigned short* G   = wbf + (size_t)P_DIM * L_DIM;            // [L][L] 128MB
    float* bv = (float*)(G + (size_t)L_DIM * L_DIM);              // [B][L] 8MB
    float* uv = bv + (size_t)B_DIM * L_DIM;                       // [B][L] 8MB
    unsigned short* a0 = (unsigned short*)(uv + (size_t)B_DIM * L_DIM);  // 4MB
    unsigned short* a1 = a0 + (size_t)B_DIM * L_DIM;              // 4MB
    unsigned short* xbf = a1 + (size_t)B_DIM * L_DIM;             // 2MB

    // casts
    cast_x_kernel<<<(B_DIM * P_DIM / 4 + 255) / 256, 256, 0, stream>>>(x, xbf, B_DIM * P_DIM);
    cast_transpose_w<<<dim3(L_DIM / 32, P_DIM / 32), dim3(32, 8), 0, stream>>>(w, wbf, wT);

    // gram: G[L,L] = wT @ wT^T - I   (A=wT, Bt=wT, K=P)
    gemm_nt<128, 128, 64, 64, 64, 0><<<dim3(L_DIM / 128, L_DIM / 128), 256, 0, stream>>>(
        wT, wT, L_DIM, P_DIM, nullptr, G, nullptr, nullptr, nullptr);

    // b = x @ w  (A=xbf, Bt=wT, K=P); epilogue: b, u=0.1b, a0=thr(u)
    gemm_nt<64, 128, 64, 64, 32, 1><<<dim3(L_DIM / 128, B_DIM / 64), 256, 0, stream>>>(
        xbf, wT, L_DIM, P_DIM, bv, nullptr, nullptr, uv, a0);

    // 48 remaining scan steps: u = 0.9u + 0.1b - 0.1*(a@G); a' = thr(u)
    unsigned short* ac = a0; unsigned short* an = a1;
    for (int it = 0; it < NSTEPS - 2; ++it) {
        gemm_nt<64, 128, 64, 64, 32, 2><<<dim3(L_DIM / 128, B_DIM / 64), 256, 0, stream>>>(
            ac, G, L_DIM, L_DIM, nullptr, nullptr, bv, uv, an);
        unsigned short* t = ac; ac = an; an = t;
    }

    // recon = a_final @ w^T  (A=ac, Bt=wbf [P][L], K=L)
    gemm_nt<64, 128, 64, 64, 32, 3><<<dim3(P_DIM / 128, B_DIM / 64), 256, 0, stream>>>(
        ac, wbf, P_DIM, L_DIM, out, nullptr, nullptr, nullptr, nullptr);
}

// Round 2
// 6128.577 us; speedup vs baseline: 1.1744x; 1.1744x over previous
//
#include <hip/hip_runtime.h>
#include <stdint.h>

#define B_DIM 256
#define P_DIM 4096
#define L_DIM 8192
#define NSTEPS 50
#define STEP 0.1f
#define LAM 0.1f

typedef __attribute__((ext_vector_type(8))) short bf16x8;
typedef __attribute__((ext_vector_type(4))) float f32x4;

__device__ __forceinline__ unsigned short f2bf(float f) {
    union { float f; uint32_t u; } x; x.f = f;
    uint32_t r = (x.u + 0x7FFF + ((x.u >> 16) & 1)) >> 16;
    return (unsigned short)r;
}

// ---------------- cast x (f32 -> bf16), vectorized ----------------
__global__ void cast_x_kernel(const float* __restrict__ in, unsigned short* __restrict__ out, int n) {
    int i = (blockIdx.x * blockDim.x + threadIdx.x) * 4;
    if (i < n) {
        float4 v = *(const float4*)&in[i];
        ushort4 o;
        o.x = f2bf(v.x); o.y = f2bf(v.y); o.z = f2bf(v.z); o.w = f2bf(v.w);
        *(ushort4*)&out[i] = o;
    }
}

// ------------- cast + transpose w: w[P][L] f32 -> w_bf[P][L], wT_bf[L][P] -------------
__global__ void cast_transpose_w(const float* __restrict__ w,
                                 unsigned short* __restrict__ w_bf,
                                 unsigned short* __restrict__ wT_bf) {
    __shared__ float tile[32][33];
    int c0 = blockIdx.x * 32;  // latent (col of w)
    int r0 = blockIdx.y * 32;  // pixel (row of w)
    int tx = threadIdx.x, ty = threadIdx.y;  // 32 x 8
#pragma unroll
    for (int i = ty; i < 32; i += 8) {
        float v = w[(size_t)(r0 + i) * L_DIM + c0 + tx];
        tile[i][tx] = v;
        w_bf[(size_t)(r0 + i) * L_DIM + c0 + tx] = f2bf(v);
    }
    __syncthreads();
#pragma unroll
    for (int i = ty; i < 32; i += 8) {
        wT_bf[(size_t)(c0 + i) * P_DIM + r0 + tx] = f2bf(tile[tx][i]);
    }
}

// ---------------- NT GEMM: C[M,N] = A[M,K] @ Bt[N,K]^T, bf16 in, f32 accum ----------------
// LDS tiles are stored XOR-swizzled (T2, rule #21 both-sides):
//   LDS[row][slot] holds global[row][slot ^ (row&7)]   (slot = 16B unit, 8 per BK=64 row)
// Staging keeps global_load_lds's linear dest and permutes the SOURCE column per lane;
// fragment reads apply the same XOR. 16 fragment lanes -> rows 0..15 hit all 8 slots
// twice -> 2-way bank aliasing (free, m136) instead of 16-way.
// EPI: 0 = gram (C_bf16 = acc - I)
//      1 = b    (b=acc; u=0.1*acc; a=thr(u))
//      2 = iter (u = 0.9u + 0.1b - 0.1*acc; a=thr(u))
//      3 = recon (Cf = acc)
template <int BM, int BN, int BK, int WM, int WN, int EPI>
__global__ __launch_bounds__((BM / WM) * (BN / WN) * 64)
void gemm_nt(const unsigned short* __restrict__ A,
             const unsigned short* __restrict__ Bt,
             int N, int K,
             float* __restrict__ Cf, unsigned short* __restrict__ Cbf,
             const float* __restrict__ bvec, float* __restrict__ uvec,
             unsigned short* __restrict__ aout) {
    constexpr int NWAVES = (BM / WM) * (BN / WN);
    constexpr int WN_CNT = BN / WN;
    constexpr int MF = WM / 16, NF = WN / 16;
    static_assert(BK == 64, "swizzle hardcoded for BK=64 (8 x 16B slots/row)");

    __shared__ __align__(16) unsigned short As[BM * BK];
    __shared__ __align__(16) unsigned short Bs[BN * BK];

    const int tid = threadIdx.x;
    const int w = tid >> 6;
    const int l = tid & 63;
    const int wr = w / WN_CNT, wc = w % WN_CNT;
    const int row0 = blockIdx.y * BM;
    const int col0 = blockIdx.x * BN;

    f32x4 acc[MF][NF] = {};

    const int lrow = l >> 3;                     // row within 8-row chunk (0..7)
    const int lcol = (((l & 7) ^ lrow) * 8);     // SWIZZLED source k-offset (elements)

    for (int k0 = 0; k0 < K; k0 += BK) {
        // stage A tile (BM x BK) via async global->LDS, 16B/lane, source pre-swizzled
#pragma unroll
        for (int i = 0; i < BM / (8 * NWAVES); ++i) {
            int chunk = i * NWAVES + w;
            const unsigned short* g = A + (size_t)(row0 + chunk * 8 + lrow) * K + (k0 + lcol);
            __builtin_amdgcn_global_load_lds(
                (const __attribute__((address_space(1))) void*)g,
                (__attribute__((address_space(3))) void*)(As + chunk * 512), 16, 0, 0);
        }
        // stage Bt tile (BN x BK)
#pragma unroll
        for (int i = 0; i < BN / (8 * NWAVES); ++i) {
            int chunk = i * NWAVES + w;
            const unsigned short* g = Bt + (size_t)(col0 + chunk * 8 + lrow) * K + (k0 + lcol);
            __builtin_amdgcn_global_load_lds(
                (const __attribute__((address_space(1))) void*)g,
                (__attribute__((address_space(3))) void*)(Bs + chunk * 512), 16, 0, 0);
        }
        asm volatile("s_waitcnt vmcnt(0)" ::: "memory");
        __syncthreads();

#pragma unroll
        for (int kk = 0; kk < BK; kk += 32) {
            const int kb = kk + (l >> 4) * 8;    // k element offset (multiple of 8)
            const int kslot = kb >> 3;           // 16B slot index 0..7
            bf16x8 af[MF], bfr[NF];
#pragma unroll
            for (int mf = 0; mf < MF; ++mf) {
                const int arow = wr * WM + mf * 16 + (l & 15);
                af[mf] = *(const bf16x8*)&As[arow * BK + ((kslot ^ (arow & 7)) << 3)];
            }
#pragma unroll
            for (int nf = 0; nf < NF; ++nf) {
                const int brow = wc * WN + nf * 16 + (l & 15);
                bfr[nf] = *(const bf16x8*)&Bs[brow * BK + ((kslot ^ (brow & 7)) << 3)];
            }
#pragma unroll
            for (int mf = 0; mf < MF; ++mf)
#pragma unroll
                for (int nf = 0; nf < NF; ++nf)
                    acc[mf][nf] = __builtin_amdgcn_mfma_f32_16x16x32_bf16(
                        af[mf], bfr[nf], acc[mf][nf], 0, 0, 0);
        }
        __syncthreads();
    }

    // epilogue: C/D layout col = l&15, row = (l>>4)*4 + j  [m89-verified]
    const int er = (l >> 4) * 4;
    const int ec = l & 15;
#pragma unroll
    for (int mf = 0; mf < MF; ++mf) {
#pragma unroll
        for (int nf = 0; nf < NF; ++nf) {
#pragma unroll
            for (int j = 0; j < 4; ++j) {
                int gr = row0 + wr * WM + mf * 16 + er + j;
                int gc = col0 + wc * WN + nf * 16 + ec;
                size_t idx = (size_t)gr * N + gc;
                float v = acc[mf][nf][j];
                if constexpr (EPI == 0) {
                    if (gr == gc) v -= 1.0f;
                    Cbf[idx] = f2bf(v);
                } else if constexpr (EPI == 1) {
                    Cf[idx] = v;
                    float u0 = STEP * v;
                    uvec[idx] = u0;
                    float a = (u0 > LAM) ? (u0 - LAM) : 0.0f;
                    aout[idx] = f2bf(a);
                } else if constexpr (EPI == 2) {
                    float un = (1.0f - STEP) * uvec[idx] + STEP * bvec[idx] - STEP * v;
                    uvec[idx] = un;
                    float a = (un > LAM) ? (un - LAM) : 0.0f;
                    aout[idx] = f2bf(a);
                } else {
                    Cf[idx] = v;
                }
            }
        }
    }
}

extern "C" void kernel_launch(void* const* d_in, const int* in_sizes, int n_in,
                              void* d_out, int out_size, void* d_ws, size_t ws_size,
                              hipStream_t stream) {
    (void)in_sizes; (void)n_in; (void)out_size; (void)ws_size;
    const float* x = (const float*)d_in[0];
    const float* w = (const float*)d_in[1];
    float* out = (float*)d_out;

    char* ws = (char*)d_ws;
    unsigned short* wT  = (unsigned short*)ws;                    // [L][P] 64MB
    unsigned short* wbf = wT + (size_t)L_DIM * P_DIM;             // [P][L] 64MB
    unsigned short* G   = wbf + (size_t)P_DIM * L_DIM;            // [L][L] 128MB
    float* bv = (float*)(G + (size_t)L_DIM * L_DIM);              // [B][L] 8MB
    float* uv = bv + (size_t)B_DIM * L_DIM;                       // [B][L] 8MB
    unsigned short* a0 = (unsigned short*)(uv + (size_t)B_DIM * L_DIM);  // 4MB
    unsigned short* a1 = a0 + (size_t)B_DIM * L_DIM;              // 4MB
    unsigned short* xbf = a1 + (size_t)B_DIM * L_DIM;             // 2MB

    // casts
    cast_x_kernel<<<(B_DIM * P_DIM / 4 + 255) / 256, 256, 0, stream>>>(x, xbf, B_DIM * P_DIM);
    cast_transpose_w<<<dim3(L_DIM / 32, P_DIM / 32), dim3(32, 8), 0, stream>>>(w, wbf, wT);

    // gram: G[L,L] = wT @ wT^T - I   (A=wT, Bt=wT, K=P)
    gemm_nt<128, 128, 64, 64, 64, 0><<<dim3(L_DIM / 128, L_DIM / 128), 256, 0, stream>>>(
        wT, wT, L_DIM, P_DIM, nullptr, G, nullptr, nullptr, nullptr);

    // b = x @ w  (A=xbf, Bt=wT, K=P); epilogue: b, u=0.1b, a0=thr(u)
    gemm_nt<64, 128, 64, 64, 32, 1><<<dim3(L_DIM / 128, B_DIM / 64), 256, 0, stream>>>(
        xbf, wT, L_DIM, P_DIM, bv, nullptr, nullptr, uv, a0);

    // 48 remaining scan steps: u = 0.9u + 0.1b - 0.1*(a@G); a' = thr(u)
    unsigned short* ac = a0; unsigned short* an = a1;
    for (int it = 0; it < NSTEPS - 2; ++it) {
        gemm_nt<64, 128, 64, 64, 32, 2><<<dim3(L_DIM / 128, B_DIM / 64), 256, 0, stream>>>(
            ac, G, L_DIM, L_DIM, nullptr, nullptr, bv, uv, an);
        unsigned short* t = ac; ac = an; an = t;
    }

    // recon = a_final @ w^T  (A=ac, Bt=wbf [P][L], K=L)
    gemm_nt<64, 128, 64, 64, 32, 3><<<dim3(P_DIM / 128, B_DIM / 64), 256, 0, stream>>>(
        ac, wbf, P_DIM, L_DIM, out, nullptr, nullptr, nullptr, nullptr);
}

// Round 3
// 5182.395 us; speedup vs baseline: 1.3889x; 1.1826x over previous
//
#include <hip/hip_runtime.h>
#include <stdint.h>

#define B_DIM 256
#define P_DIM 4096
#define L_DIM 8192
#define NSTEPS 50
#define STEP 0.1f
#define LAM 0.1f

typedef __attribute__((ext_vector_type(8))) short bf16x8;
typedef __attribute__((ext_vector_type(4))) float f32x4;

__device__ __forceinline__ unsigned short f2bf(float f) {
    union { float f; uint32_t u; } x; x.f = f;
    uint32_t r = (x.u + 0x7FFF + ((x.u >> 16) & 1)) >> 16;
    return (unsigned short)r;
}

// ---------------- cast x (f32 -> bf16), vectorized ----------------
__global__ void cast_x_kernel(const float* __restrict__ in, unsigned short* __restrict__ out, int n) {
    int i = (blockIdx.x * blockDim.x + threadIdx.x) * 4;
    if (i < n) {
        float4 v = *(const float4*)&in[i];
        ushort4 o;
        o.x = f2bf(v.x); o.y = f2bf(v.y); o.z = f2bf(v.z); o.w = f2bf(v.w);
        *(ushort4*)&out[i] = o;
    }
}

// ------------- cast + transpose w: w[P][L] f32 -> w_bf[P][L], wT_bf[L][P] -------------
__global__ void cast_transpose_w(const float* __restrict__ w,
                                 unsigned short* __restrict__ w_bf,
                                 unsigned short* __restrict__ wT_bf) {
    __shared__ float tile[32][33];
    int c0 = blockIdx.x * 32;  // latent (col of w)
    int r0 = blockIdx.y * 32;  // pixel (row of w)
    int tx = threadIdx.x, ty = threadIdx.y;  // 32 x 8
#pragma unroll
    for (int i = ty; i < 32; i += 8) {
        float v = w[(size_t)(r0 + i) * L_DIM + c0 + tx];
        tile[i][tx] = v;
        w_bf[(size_t)(r0 + i) * L_DIM + c0 + tx] = f2bf(v);
    }
    __syncthreads();
#pragma unroll
    for (int i = ty; i < 32; i += 8) {
        wT_bf[(size_t)(c0 + i) * P_DIM + r0 + tx] = f2bf(tile[tx][i]);
    }
}

// ---------------- NT GEMM: C[M,N] = A[M,K] @ Bt[N,K]^T, bf16 in, f32 accum ----------------
// - LDS XOR-swizzled (T2, both-sides): LDS[row][slot] = global[row][slot ^ (row&7)],
//   staged via linear-dest global_load_lds with pre-swizzled per-lane SOURCE column.
// - Double-buffered, 1-deep prefetch (T3-minimal 2-phase): stage(t+1) issued BEFORE
//   compute(t); one drain+barrier per tile; main loop unrolled x2 so buffer index is
//   compile-time (rule #20 hygiene for address calc).
// EPI: 0 = gram (C_bf16 = acc - I)
//      1 = b    (b=acc; u=0.1*acc; a=thr(u))
//      2 = iter (u = 0.9u + 0.1b - 0.1*acc; a=thr(u))
//      3 = recon (Cf = acc)
template <int BM, int BN, int BK, int WMC, int WNC, int EPI>
__global__ __launch_bounds__(WMC * WNC * 64)
void gemm_nt(const unsigned short* __restrict__ A,
             const unsigned short* __restrict__ Bt,
             int N, int K,
             float* __restrict__ Cf, unsigned short* __restrict__ Cbf,
             const float* __restrict__ bvec, float* __restrict__ uvec,
             unsigned short* __restrict__ aout) {
    constexpr int NWAVES = WMC * WNC;
    constexpr int WM = BM / WMC, WN = BN / WNC;
    constexpr int MF = WM / 16, NF = WN / 16;
    constexpr int ACH = BM / (8 * NWAVES);   // A 8-row chunks staged per wave
    constexpr int BCH = BN / (8 * NWAVES);
    static_assert(BK == 64, "swizzle hardcoded for BK=64 (8 x 16B slots/row)");
    static_assert(ACH >= 1 && BCH >= 1, "tile too small for wave count");

    __shared__ __align__(16) unsigned short As[2][BM * BK];
    __shared__ __align__(16) unsigned short Bs[2][BN * BK];

    const int tid = threadIdx.x;
    const int w = tid >> 6;
    const int l = tid & 63;
    const int wr = w / WNC, wc = w % WNC;
    const int row0 = blockIdx.y * BM;
    const int col0 = blockIdx.x * BN;

    const int lrow = l >> 3;                     // row within 8-row chunk (0..7)
    const int lcol = (((l & 7) ^ lrow) * 8);     // SWIZZLED source k-offset (elements)

    const unsigned short* gA = A + (size_t)(row0 + lrow) * K + lcol;
    const unsigned short* gB = Bt + (size_t)(col0 + lrow) * K + lcol;

    auto stage = [&](int buf, int k0) {
#pragma unroll
        for (int i = 0; i < ACH; ++i) {
            const int chunk = i * NWAVES + w;
            __builtin_amdgcn_global_load_lds(
                (const __attribute__((address_space(1))) void*)(gA + (size_t)chunk * 8 * K + k0),
                (__attribute__((address_space(3))) void*)(&As[buf][chunk * 512]), 16, 0, 0);
        }
#pragma unroll
        for (int i = 0; i < BCH; ++i) {
            const int chunk = i * NWAVES + w;
            __builtin_amdgcn_global_load_lds(
                (const __attribute__((address_space(1))) void*)(gB + (size_t)chunk * 8 * K + k0),
                (__attribute__((address_space(3))) void*)(&Bs[buf][chunk * 512]), 16, 0, 0);
        }
    };

    f32x4 acc[MF][NF] = {};

    auto compute = [&](int buf) {
#pragma unroll
        for (int kk = 0; kk < BK; kk += 32) {
            const int kslot = (kk >> 3) + (l >> 4);  // 16B slot index 0..7
            bf16x8 af[MF], bfr[NF];
#pragma unroll
            for (int mf = 0; mf < MF; ++mf) {
                const int arow = wr * WM + mf * 16 + (l & 15);
                af[mf] = *(const bf16x8*)&As[buf][arow * BK + ((kslot ^ (arow & 7)) << 3)];
            }
#pragma unroll
            for (int nf = 0; nf < NF; ++nf) {
                const int brow = wc * WN + nf * 16 + (l & 15);
                bfr[nf] = *(const bf16x8*)&Bs[buf][brow * BK + ((kslot ^ (brow & 7)) << 3)];
            }
#pragma unroll
            for (int mf = 0; mf < MF; ++mf)
#pragma unroll
                for (int nf = 0; nf < NF; ++nf)
                    acc[mf][nf] = __builtin_amdgcn_mfma_f32_16x16x32_bf16(
                        af[mf], bfr[nf], acc[mf][nf], 0, 0, 0);
        }
    };

    const int nt = K / BK;   // K is a multiple of 128 everywhere -> nt even
    stage(0, 0);
#pragma unroll 1
    for (int t = 0; t < nt; t += 2) {
        asm volatile("s_waitcnt vmcnt(0)" ::: "memory");
        __syncthreads();
        stage(1, (t + 1) * BK);        // prefetch overlaps compute(0)
        compute(0);
        asm volatile("s_waitcnt vmcnt(0)" ::: "memory");
        __syncthreads();
        if (t + 2 < nt) stage(0, (t + 2) * BK);
        compute(1);
    }

    // epilogue: C/D layout col = l&15, row = (l>>4)*4 + j  [m89-verified]
    const int er = (l >> 4) * 4;
    const int ec = l & 15;
#pragma unroll
    for (int mf = 0; mf < MF; ++mf) {
#pragma unroll
        for (int nf = 0; nf < NF; ++nf) {
#pragma unroll
            for (int j = 0; j < 4; ++j) {
                int gr = row0 + wr * WM + mf * 16 + er + j;
                int gc = col0 + wc * WN + nf * 16 + ec;
                size_t idx = (size_t)gr * N + gc;
                float v = acc[mf][nf][j];
                if constexpr (EPI == 0) {
                    if (gr == gc) v -= 1.0f;
                    Cbf[idx] = f2bf(v);
                } else if constexpr (EPI == 1) {
                    Cf[idx] = v;
                    float u0 = STEP * v;
                    uvec[idx] = u0;
                    float a = (u0 > LAM) ? (u0 - LAM) : 0.0f;
                    aout[idx] = f2bf(a);
                } else if constexpr (EPI == 2) {
                    float un = (1.0f - STEP) * uvec[idx] + STEP * bvec[idx] - STEP * v;
                    uvec[idx] = un;
                    float a = (un > LAM) ? (un - LAM) : 0.0f;
                    aout[idx] = f2bf(a);
                } else {
                    Cf[idx] = v;
                }
            }
        }
    }
}

extern "C" void kernel_launch(void* const* d_in, const int* in_sizes, int n_in,
                              void* d_out, int out_size, void* d_ws, size_t ws_size,
                              hipStream_t stream) {
    (void)in_sizes; (void)n_in; (void)out_size; (void)ws_size;
    const float* x = (const float*)d_in[0];
    const float* w = (const float*)d_in[1];
    float* out = (float*)d_out;

    char* ws = (char*)d_ws;
    unsigned short* wT  = (unsigned short*)ws;                    // [L][P] 64MB
    unsigned short* wbf = wT + (size_t)L_DIM * P_DIM;             // [P][L] 64MB
    unsigned short* G   = wbf + (size_t)P_DIM * L_DIM;            // [L][L] 128MB
    float* bv = (float*)(G + (size_t)L_DIM * L_DIM);              // [B][L] 8MB
    float* uv = bv + (size_t)B_DIM * L_DIM;                       // [B][L] 8MB
    unsigned short* a0 = (unsigned short*)(uv + (size_t)B_DIM * L_DIM);  // 4MB
    unsigned short* a1 = a0 + (size_t)B_DIM * L_DIM;              // 4MB
    unsigned short* xbf = a1 + (size_t)B_DIM * L_DIM;             // 2MB

    // casts
    cast_x_kernel<<<(B_DIM * P_DIM / 4 + 255) / 256, 256, 0, stream>>>(x, xbf, B_DIM * P_DIM);
    cast_transpose_w<<<dim3(L_DIM / 32, P_DIM / 32), dim3(32, 8), 0, stream>>>(w, wbf, wT);

    // gram: G[L,L] = wT @ wT^T - I   (A=wT, Bt=wT, K=P)  128x128 tile, 8 waves
    gemm_nt<128, 128, 64, 2, 4, 0><<<dim3(L_DIM / 128, L_DIM / 128), 512, 0, stream>>>(
        wT, wT, L_DIM, P_DIM, nullptr, G, nullptr, nullptr, nullptr);

    // b = x @ w  (A=xbf, Bt=wT, K=P); epilogue: b, u=0.1b, a0=thr(u)
    gemm_nt<64, 128, 64, 2, 4, 1><<<dim3(L_DIM / 128, B_DIM / 64), 512, 0, stream>>>(
        xbf, wT, L_DIM, P_DIM, bv, nullptr, nullptr, uv, a0);

    // 48 remaining scan steps: u = 0.9u + 0.1b - 0.1*(a@G); a' = thr(u)
    unsigned short* ac = a0; unsigned short* an = a1;
    for (int it = 0; it < NSTEPS - 2; ++it) {
        gemm_nt<64, 128, 64, 2, 4, 2><<<dim3(L_DIM / 128, B_DIM / 64), 512, 0, stream>>>(
            ac, G, L_DIM, L_DIM, nullptr, nullptr, bv, uv, an);
        unsigned short* t = ac; ac = an; an = t;
    }

    // recon = a_final @ w^T  (A=ac, Bt=wbf [P][L], K=L)  64x64 tile -> 256 blocks
    gemm_nt<64, 64, 64, 2, 4, 3><<<dim3(P_DIM / 64, B_DIM / 64), 512, 0, stream>>>(
        ac, wbf, P_DIM, L_DIM, out, nullptr, nullptr, nullptr, nullptr);
}

// Round 4
// 2983.393 us; speedup vs baseline: 2.4126x; 1.7371x over previous
//
#include <hip/hip_runtime.h>
#include <stdint.h>

#define B_DIM 256
#define P_DIM 4096
#define L_DIM 8192
#define NSTEPS 50
#define STEP 0.1f
#define LAM 0.1f

typedef __attribute__((ext_vector_type(8))) short bf16x8;
typedef __attribute__((ext_vector_type(4))) float f32x4;

__device__ __forceinline__ unsigned short f2bf(float f) {
    union { float f; uint32_t u; } x; x.f = f;
    uint32_t r = (x.u + 0x7FFF + ((x.u >> 16) & 1)) >> 16;
    return (unsigned short)r;
}

// ---------------- cast x (f32 -> bf16), vectorized ----------------
__global__ void cast_x_kernel(const float* __restrict__ in, unsigned short* __restrict__ out, int n) {
    int i = (blockIdx.x * blockDim.x + threadIdx.x) * 4;
    if (i < n) {
        float4 v = *(const float4*)&in[i];
        ushort4 o;
        o.x = f2bf(v.x); o.y = f2bf(v.y); o.z = f2bf(v.z); o.w = f2bf(v.w);
        *(ushort4*)&out[i] = o;
    }
}

// ------------- cast + transpose w: w[P][L] f32 -> w_bf[P][L], wT_bf[L][P] -------------
__global__ void cast_transpose_w(const float* __restrict__ w,
                                 unsigned short* __restrict__ w_bf,
                                 unsigned short* __restrict__ wT_bf) {
    __shared__ float tile[32][33];
    int c0 = blockIdx.x * 32;
    int r0 = blockIdx.y * 32;
    int tx = threadIdx.x, ty = threadIdx.y;  // 32 x 8
#pragma unroll
    for (int i = ty; i < 32; i += 8) {
        float v = w[(size_t)(r0 + i) * L_DIM + c0 + tx];
        tile[i][tx] = v;
        w_bf[(size_t)(r0 + i) * L_DIM + c0 + tx] = f2bf(v);
    }
    __syncthreads();
#pragma unroll
    for (int i = ty; i < 32; i += 8) {
        wT_bf[(size_t)(c0 + i) * P_DIM + r0 + tx] = f2bf(tile[tx][i]);
    }
}

// ======================= gram GEMM (round-3 structure, unchanged) =======================
template <int BM, int BN, int BK, int WMC, int WNC>
__global__ __launch_bounds__(WMC * WNC * 64)
void gemm_gram(const unsigned short* __restrict__ A,
               const unsigned short* __restrict__ Bt,
               int N, int K, unsigned short* __restrict__ Cbf) {
    constexpr int NWAVES = WMC * WNC;
    constexpr int WM = BM / WMC, WN = BN / WNC;
    constexpr int MF = WM / 16, NF = WN / 16;
    constexpr int ACH = BM / (8 * NWAVES);
    constexpr int BCH = BN / (8 * NWAVES);
    static_assert(BK == 64, "swizzle hardcoded for BK=64");

    __shared__ __align__(16) unsigned short As[2][BM * BK];
    __shared__ __align__(16) unsigned short Bs[2][BN * BK];

    const int tid = threadIdx.x;
    const int w = tid >> 6;
    const int l = tid & 63;
    const int wr = w / WNC, wc = w % WNC;
    const int row0 = blockIdx.y * BM;
    const int col0 = blockIdx.x * BN;

    const int lrow = l >> 3;
    const int lcol = (((l & 7) ^ lrow) * 8);

    const unsigned short* gA = A + (size_t)(row0 + lrow) * K + lcol;
    const unsigned short* gB = Bt + (size_t)(col0 + lrow) * K + lcol;

    auto stage = [&](int buf, int k0) {
#pragma unroll
        for (int i = 0; i < ACH; ++i) {
            const int chunk = i * NWAVES + w;
            __builtin_amdgcn_global_load_lds(
                (const __attribute__((address_space(1))) void*)(gA + (size_t)chunk * 8 * K + k0),
                (__attribute__((address_space(3))) void*)(&As[buf][chunk * 512]), 16, 0, 0);
        }
#pragma unroll
        for (int i = 0; i < BCH; ++i) {
            const int chunk = i * NWAVES + w;
            __builtin_amdgcn_global_load_lds(
                (const __attribute__((address_space(1))) void*)(gB + (size_t)chunk * 8 * K + k0),
                (__attribute__((address_space(3))) void*)(&Bs[buf][chunk * 512]), 16, 0, 0);
        }
    };

    f32x4 acc[MF][NF] = {};

    auto compute = [&](int buf) {
#pragma unroll
        for (int kk = 0; kk < BK; kk += 32) {
            const int kslot = (kk >> 3) + (l >> 4);
            bf16x8 af[MF], bfr[NF];
#pragma unroll
            for (int mf = 0; mf < MF; ++mf) {
                const int arow = wr * WM + mf * 16 + (l & 15);
                af[mf] = *(const bf16x8*)&As[buf][arow * BK + ((kslot ^ (arow & 7)) << 3)];
            }
#pragma unroll
            for (int nf = 0; nf < NF; ++nf) {
                const int brow = wc * WN + nf * 16 + (l & 15);
                bfr[nf] = *(const bf16x8*)&Bs[buf][brow * BK + ((kslot ^ (brow & 7)) << 3)];
            }
#pragma unroll
            for (int mf = 0; mf < MF; ++mf)
#pragma unroll
                for (int nf = 0; nf < NF; ++nf)
                    acc[mf][nf] = __builtin_amdgcn_mfma_f32_16x16x32_bf16(
                        af[mf], bfr[nf], acc[mf][nf], 0, 0, 0);
        }
    };

    const int nt = K / BK;
    stage(0, 0);
#pragma unroll 1
    for (int t = 0; t < nt; t += 2) {
        asm volatile("s_waitcnt vmcnt(0)" ::: "memory");
        __syncthreads();
        stage(1, (t + 1) * BK);
        compute(0);
        asm volatile("s_waitcnt vmcnt(0)" ::: "memory");
        __syncthreads();
        if (t + 2 < nt) stage(0, (t + 2) * BK);
        compute(1);
    }

    const int er = (l >> 4) * 4;
    const int ec = l & 15;
#pragma unroll
    for (int mf = 0; mf < MF; ++mf)
#pragma unroll
        for (int nf = 0; nf < NF; ++nf)
#pragma unroll
            for (int j = 0; j < 4; ++j) {
                int gr = row0 + wr * WM + mf * 16 + er + j;
                int gc = col0 + wc * WN + nf * 16 + ec;
                float v = acc[mf][nf][j];
                if (gr == gc) v -= 1.0f;
                Cbf[(size_t)gr * N + gc] = f2bf(v);
            }
}

// ======================= pipelined GEMM (iter / b / recon) =======================
// C[256, NN] = A[256, KK] @ Bt[NN, KK]^T
// - T2 XOR-swizzle (both-sides, as gram)
// - T4: NBUF=4, 3-ahead prefetch, counted vmcnt, raw s_barrier (no vmcnt(0) drain
//   in steady state -- __syncthreads would emit one, so it is NOT used here)
// - T1: XCD panel mapping: id%8 = XCD, consecutive id/8 = 4 row-blocks of one
//   G column-panel -> panel fetched into one XCD's L2, shared by its 4 consumers.
// EPI: 1 = b (b=acc; u=0.1acc; a=thr); 2 = iter (u=0.9u+0.1b-0.1acc; a=thr); 3 = recon (Cf=acc)
template <int BM, int BN, int BK, int WMC, int WNC, int EPI, int NN, int KK>
__global__ __launch_bounds__(WMC * WNC * 64)
void gemm_pipe(const unsigned short* __restrict__ A,
               const unsigned short* __restrict__ Bt,
               float* __restrict__ Cf,
               const float* __restrict__ bvec, float* __restrict__ uvec,
               unsigned short* __restrict__ aout) {
    constexpr int NWAVES = WMC * WNC;
    constexpr int WM = BM / WMC, WN = BN / WNC;
    constexpr int MF = WM / 16, NF = WN / 16;
    constexpr int ACH = BM / (8 * NWAVES);
    constexpr int BCH = BN / (8 * NWAVES);
    constexpr int LPS = ACH + BCH;        // gload_lds per thread per stage
    constexpr int NT = KK / BK;
    constexpr int GX = NN / BN;
    constexpr int PPX = GX / 8;           // panels per XCD
    static_assert(BK == 64 && BM == 64, "geometry");
    static_assert(NT % 4 == 0 && GX % 8 == 0 && ACH >= 1 && BCH >= 1, "geometry");

    __shared__ __align__(16) unsigned short As[4][BM * BK];
    __shared__ __align__(16) unsigned short Bs[4][BN * BK];

    const int tid = threadIdx.x;
    const int w = tid >> 6;
    const int l = tid & 63;
    const int wr = w / WNC, wc = w % WNC;

    // XCD mapping: 4 consecutive k on one XCD = the 4 row-blocks of one panel
    const int id = blockIdx.x;
    const int bx = (id & 7) * PPX + ((id >> 3) >> 2);
    const int by = (id >> 3) & 3;
    const int row0 = by * BM;
    const int col0 = bx * BN;

    const int lrow = l >> 3;
    const int lcol = (((l & 7) ^ lrow) * 8);   // pre-swizzled source column

    const unsigned short* gA = A + (size_t)(row0 + lrow) * KK + lcol;
    const unsigned short* gB = Bt + (size_t)(col0 + lrow) * KK + lcol;

    auto stage = [&](int buf, int k0) {
#pragma unroll
        for (int i = 0; i < ACH; ++i) {
            const int chunk = i * NWAVES + w;
            __builtin_amdgcn_global_load_lds(
                (const __attribute__((address_space(1))) void*)(gA + (size_t)chunk * 8 * KK + k0),
                (__attribute__((address_space(3))) void*)(&As[buf][chunk * 512]), 16, 0, 0);
        }
#pragma unroll
        for (int i = 0; i < BCH; ++i) {
            const int chunk = i * NWAVES + w;
            __builtin_amdgcn_global_load_lds(
                (const __attribute__((address_space(1))) void*)(gB + (size_t)chunk * 8 * KK + k0),
                (__attribute__((address_space(3))) void*)(&Bs[buf][chunk * 512]), 16, 0, 0);
        }
    };

    f32x4 acc[MF][NF] = {};

    auto compute = [&](int buf) {
#pragma unroll
        for (int kk = 0; kk < BK; kk += 32) {
            const int kslot = (kk >> 3) + (l >> 4);
            bf16x8 af[MF], bfr[NF];
#pragma unroll
            for (int mf = 0; mf < MF; ++mf) {
                const int arow = wr * WM + mf * 16 + (l & 15);
                af[mf] = *(const bf16x8*)&As[buf][arow * BK + ((kslot ^ (arow & 7)) << 3)];
            }
#pragma unroll
            for (int nf = 0; nf < NF; ++nf) {
                const int brow = wc * WN + nf * 16 + (l & 15);
                bfr[nf] = *(const bf16x8*)&Bs[buf][brow * BK + ((kslot ^ (brow & 7)) << 3)];
            }
#pragma unroll
            for (int mf = 0; mf < MF; ++mf)
#pragma unroll
                for (int nf = 0; nf < NF; ++nf)
                    acc[mf][nf] = __builtin_amdgcn_mfma_f32_16x16x32_bf16(
                        af[mf], bfr[nf], acc[mf][nf], 0, 0, 0);
        }
    };

    // phase: wait own stage(t) landed (counted!), barrier (others' too), issue t+3, compute t
#define PH(BUF, TT, WAITN, DOSTG)                                            \
    asm volatile("s_waitcnt vmcnt(%0)" ::"i"(WAITN) : "memory");             \
    __builtin_amdgcn_s_barrier();                                            \
    asm volatile("" ::: "memory");                                           \
    if (DOSTG) stage((BUF + 3) & 3, ((TT) + 3) * BK);                        \
    compute(BUF);

    stage(0, 0);
    stage(1, BK);
    stage(2, 2 * BK);
#pragma unroll 1
    for (int t = 0; t < NT - 4; t += 4) {
        PH(0, t + 0, 2 * LPS, true)
        PH(1, t + 1, 2 * LPS, true)
        PH(2, t + 2, 2 * LPS, true)
        PH(3, t + 3, 2 * LPS, true)
    }
    PH(0, NT - 4, 2 * LPS, true)   // stages NT-1
    PH(1, NT - 3, 2 * LPS, false)
    PH(2, NT - 2, LPS, false)
    PH(3, NT - 1, 0, false)
#undef PH

    // epilogue: C/D layout col = l&15, row = (l>>4)*4 + j
    const int er = (l >> 4) * 4;
    const int ec = l & 15;
#pragma unroll
    for (int mf = 0; mf < MF; ++mf) {
#pragma unroll
        for (int nf = 0; nf < NF; ++nf) {
#pragma unroll
            for (int j = 0; j < 4; ++j) {
                int gr = row0 + wr * WM + mf * 16 + er + j;
                int gc = col0 + wc * WN + nf * 16 + ec;
                size_t idx = (size_t)gr * NN + gc;
                float v = acc[mf][nf][j];
                if constexpr (EPI == 1) {
                    Cf[idx] = v;
                    float u0 = STEP * v;
                    uvec[idx] = u0;
                    float a = (u0 > LAM) ? (u0 - LAM) : 0.0f;
                    aout[idx] = f2bf(a);
                } else if constexpr (EPI == 2) {
                    float un = (1.0f - STEP) * uvec[idx] + STEP * bvec[idx] - STEP * v;
                    uvec[idx] = un;
                    float a = (un > LAM) ? (un - LAM) : 0.0f;
                    aout[idx] = f2bf(a);
                } else {
                    Cf[idx] = v;
                }
            }
        }
    }
}

extern "C" void kernel_launch(void* const* d_in, const int* in_sizes, int n_in,
                              void* d_out, int out_size, void* d_ws, size_t ws_size,
                              hipStream_t stream) {
    (void)in_sizes; (void)n_in; (void)out_size; (void)ws_size;
    const float* x = (const float*)d_in[0];
    const float* w = (const float*)d_in[1];
    float* out = (float*)d_out;

    char* ws = (char*)d_ws;
    unsigned short* wT  = (unsigned short*)ws;                    // [L][P] 64MB
    unsigned short* wbf = wT + (size_t)L_DIM * P_DIM;             // [P][L] 64MB
    unsigned short* G   = wbf + (size_t)P_DIM * L_DIM;            // [L][L] 128MB
    float* bv = (float*)(G + (size_t)L_DIM * L_DIM);              // [B][L] 8MB
    float* uv = bv + (size_t)B_DIM * L_DIM;                       // [B][L] 8MB
    unsigned short* a0 = (unsigned short*)(uv + (size_t)B_DIM * L_DIM);  // 4MB
    unsigned short* a1 = a0 + (size_t)B_DIM * L_DIM;              // 4MB
    unsigned short* xbf = a1 + (size_t)B_DIM * L_DIM;             // 2MB

    // casts
    cast_x_kernel<<<(B_DIM * P_DIM / 4 + 255) / 256, 256, 0, stream>>>(x, xbf, B_DIM * P_DIM);
    cast_transpose_w<<<dim3(L_DIM / 32, P_DIM / 32), dim3(32, 8), 0, stream>>>(w, wbf, wT);

    // gram: G[L,L] = wT @ wT^T - I (unchanged round-3 path, 944 TF)
    gemm_gram<128, 128, 64, 2, 4><<<dim3(L_DIM / 128, L_DIM / 128), 512, 0, stream>>>(
        wT, wT, L_DIM, P_DIM, G);

    // b = x @ w : pipelined path, K=4096
    gemm_pipe<64, 128, 64, 2, 4, 1, L_DIM, P_DIM><<<256, 512, 0, stream>>>(
        xbf, wT, bv, nullptr, uv, a0);

    // 48 scan steps: u = 0.9u + 0.1b - 0.1*(a@G); a' = thr(u)
    unsigned short* ac = a0; unsigned short* an = a1;
    for (int it = 0; it < NSTEPS - 2; ++it) {
        gemm_pipe<64, 128, 64, 2, 4, 2, L_DIM, L_DIM><<<256, 512, 0, stream>>>(
            ac, G, nullptr, bv, uv, an);
        unsigned short* t = ac; ac = an; an = t;
    }

    // recon = a_final @ w^T : BN=64 -> 256 blocks
    gemm_pipe<64, 64, 64, 2, 4, 3, P_DIM, L_DIM><<<256, 512, 0, stream>>>(
        ac, wbf, out, nullptr, nullptr, nullptr);
}